// Round 3
// baseline (188.318 us; speedup 1.0000x reference)
//
#include <hip/hip_runtime.h>
#include <hip/hip_bf16.h>

#define LRALPHA 0.2f
#define NN 8192
#define FIN 128
#define FOUT 64
#define NJC 6            // j-splits per row (3072 waves = 768 blocks, 3/CU exact)

typedef __attribute__((ext_vector_type(4))) float f32x4;
typedef __attribute__((ext_vector_type(8))) short bf16x8;
typedef __attribute__((ext_vector_type(4))) int int4v;

// ---------------------------------------------------------------------------
// kernel 1: h = inp @ W (fp32), f1 = h@a1, f2 = h@a2, hT[c][row] in bf16
// ---------------------------------------------------------------------------
__global__ __launch_bounds__(256) void prep_kernel(
    const float* __restrict__ inp, const float* __restrict__ Wg,
    const float* __restrict__ ag, float* __restrict__ f1,
    float* __restrict__ f2, unsigned short* __restrict__ hT)
{
  __shared__ alignas(16) float WlT[FOUT][FIN + 4];
  const int t = threadIdx.x;
  for (int i = t; i < FIN * FOUT; i += 256)
    WlT[i & 63][i >> 6] = Wg[i];
  __syncthreads();

  const int lane = t & 63;
  const int row0 = blockIdx.x * 16 + (t >> 6) * 4;

  float h0 = 0.f, h1 = 0.f, h2 = 0.f, h3 = 0.f;
  for (int kk = 0; kk < FIN; kk += 4) {
    f32x4 wv = *(const f32x4*)&WlT[lane][kk];
    f32x4 r0 = *(const f32x4*)&inp[(row0 + 0) * FIN + kk];
    f32x4 r1 = *(const f32x4*)&inp[(row0 + 1) * FIN + kk];
    f32x4 r2 = *(const f32x4*)&inp[(row0 + 2) * FIN + kk];
    f32x4 r3 = *(const f32x4*)&inp[(row0 + 3) * FIN + kk];
    h0 += r0[0]*wv[0] + r0[1]*wv[1] + r0[2]*wv[2] + r0[3]*wv[3];
    h1 += r1[0]*wv[0] + r1[1]*wv[1] + r1[2]*wv[2] + r1[3]*wv[3];
    h2 += r2[0]*wv[0] + r2[1]*wv[1] + r2[2]*wv[2] + r2[3]*wv[3];
    h3 += r3[0]*wv[0] + r3[1]*wv[1] + r3[2]*wv[2] + r3[3]*wv[3];
  }

  const float a1v = ag[lane], a2v = ag[64 + lane];
  float hv[4] = {h0, h1, h2, h3};
#pragma unroll
  for (int rr = 0; rr < 4; ++rr) {
    float c1 = hv[rr] * a1v;
    float c2 = hv[rr] * a2v;
#pragma unroll
    for (int off = 32; off > 0; off >>= 1) {
      c1 += __shfl_xor(c1, off);
      c2 += __shfl_xor(c2, off);
    }
    if (lane == 0) { f1[row0 + rr] = c1; f2[row0 + rr] = c2; }
    __hip_bfloat16 hb = __float2bfloat16(hv[rr]);
    hT[lane * NN + row0 + rr] = __builtin_bit_cast(unsigned short, hb);
  }
}

// ---------------------------------------------------------------------------
// kernel 2: global max of f2
// ---------------------------------------------------------------------------
__global__ __launch_bounds__(256) void f2max_kernel(
    const float* __restrict__ f2, float* __restrict__ f2m)
{
  const int t = threadIdx.x;
  float m = -1e30f;
  for (int i = t; i < NN / 4; i += 256) {
    f32x4 v = ((const f32x4*)f2)[i];
    m = fmaxf(fmaxf(m, fmaxf(v[0], v[1])), fmaxf(v[2], v[3]));
  }
#pragma unroll
  for (int off = 32; off > 0; off >>= 1)
    m = fmaxf(m, __shfl_xor(m, off));
  __shared__ float ms[4];
  if ((t & 63) == 0) ms[t >> 6] = m;
  __syncthreads();
  if (t == 0)
    f2m[0] = fmaxf(fmaxf(ms[0], ms[1]), fmaxf(ms[2], ms[3]));
}

// ---------------------------------------------------------------------------
// kernel 3: fused attention PV — NO LDS, NO BARRIERS.
// Each wave owns 16 rows x one j-chunk; P is computed directly in the MFMA
// A-fragment layout (lane l: row l&15, k = (l>>4)*8+e), B-fragments read
// straight from L2-resident hT. Partial acc/rowsum -> ws.
// Strips of 32 j; ring: adj/f2 depth-4 (HBM), bv depth-2 (L2).
// ---------------------------------------------------------------------------
__global__ __launch_bounds__(256, 3) void gat_pv(
    const int* __restrict__ adj, const float* __restrict__ f1g,
    const float* __restrict__ f2g, const float* __restrict__ f2m,
    const unsigned short* __restrict__ hTg,
    float* __restrict__ pacc, float* __restrict__ prs)
{
  const int t = threadIdx.x;
  const int l = t & 63;
  const int w = t >> 6;

  const int item = blockIdx.x * 4 + w;   // 0..3071 wave work-items
  const int rb = item / NJC;             // rowblock 0..511
  const int jc = item % NJC;             // j-chunk 0..5
  const int r0 = rb * 16;

  // strip boundaries (strips of 32 j): {0,44,88,132,176,216,256}
  const int s0 = jc * 44 - 4 * (jc > 4 ? jc - 4 : 0);
  const int s1 = s0 + (jc < 4 ? 44 : 40);

  const int row = l & 15;
  const int grp = l >> 4;                // 0..3

  const float f1v = f1g[r0 + row];
  const float fmv = f2m[0];
  float mrow = f1v + fmv;
  mrow = fmaxf(mrow, LRALPHA * mrow);    // safe upper bound on row max

  const int* adjp = adj + (size_t)(r0 + row) * NN + grp * 8;
  const float* f2p = f2g + grp * 8;
  const unsigned short* hp0 = hTg + (size_t)(0 * 16 + row) * NN + grp * 8;
  const unsigned short* hp1 = hTg + (size_t)(1 * 16 + row) * NN + grp * 8;
  const unsigned short* hp2 = hTg + (size_t)(2 * 16 + row) * NN + grp * 8;
  const unsigned short* hp3 = hTg + (size_t)(3 * 16 + row) * NN + grp * 8;

  f32x4 acc0 = {0,0,0,0}, acc1 = {0,0,0,0}, acc2 = {0,0,0,0}, acc3 = {0,0,0,0};
  float rs = 0.f;

  int4v aA0,aA1,aB0,aB1,aC0,aC1,aD0,aD1;
  f32x4 fA0,fA1,fB0,fB1,fC0,fC1,fD0,fD1;
  bf16x8 bX0,bX1,bX2,bX3,bY0,bY1,bY2,bY3;

#define PREF_AF(AJ0,AJ1,F0,F1,S)                                               \
  { int _s = (S) > 255 ? 255 : (S);                                            \
    AJ0 = __builtin_nontemporal_load((const int4v*)(adjp + _s * 32));          \
    AJ1 = __builtin_nontemporal_load((const int4v*)(adjp + _s * 32 + 4));      \
    F0 = *(const f32x4*)(f2p + _s * 32);                                       \
    F1 = *(const f32x4*)(f2p + _s * 32 + 4); }

#define PREF_BV(B0,B1,B2,B3,S)                                                 \
  { int _s = (S) > 255 ? 255 : (S);                                            \
    B0 = *(const bf16x8*)(hp0 + _s * 32);                                      \
    B1 = *(const bf16x8*)(hp1 + _s * 32);                                      \
    B2 = *(const bf16x8*)(hp2 + _s * 32);                                      \
    B3 = *(const bf16x8*)(hp3 + _s * 32); }

  PREF_AF(aA0,aA1,fA0,fA1, s0);
  PREF_AF(aB0,aB1,fB0,fB1, s0 + 1);
  PREF_AF(aC0,aC1,fC0,fC1, s0 + 2);
  PREF_AF(aD0,aD1,fD0,fD1, s0 + 3);
  PREF_BV(bX0,bX1,bX2,bX3, s0);
  PREF_BV(bY0,bY1,bY2,bY3, s0 + 1);

#define BODY(S, AJ0,AJ1,F0,F1, B0,B1,B2,B3)                                    \
  {                                                                            \
    float x0 = f1v + F0[0]; x0 = fmaxf(x0, LRALPHA * x0) - mrow;               \
    float x1 = f1v + F0[1]; x1 = fmaxf(x1, LRALPHA * x1) - mrow;               \
    float x2 = f1v + F0[2]; x2 = fmaxf(x2, LRALPHA * x2) - mrow;               \
    float x3 = f1v + F0[3]; x3 = fmaxf(x3, LRALPHA * x3) - mrow;               \
    float x4 = f1v + F1[0]; x4 = fmaxf(x4, LRALPHA * x4) - mrow;               \
    float x5 = f1v + F1[1]; x5 = fmaxf(x5, LRALPHA * x5) - mrow;               \
    float x6 = f1v + F1[2]; x6 = fmaxf(x6, LRALPHA * x6) - mrow;               \
    float x7 = f1v + F1[3]; x7 = fmaxf(x7, LRALPHA * x7) - mrow;               \
    float p0 = AJ0[0] > 0 ? __expf(x0) : 0.f;                                  \
    float p1 = AJ0[1] > 0 ? __expf(x1) : 0.f;                                  \
    float p2 = AJ0[2] > 0 ? __expf(x2) : 0.f;                                  \
    float p3 = AJ0[3] > 0 ? __expf(x3) : 0.f;                                  \
    float p4 = AJ1[0] > 0 ? __expf(x4) : 0.f;                                  \
    float p5 = AJ1[1] > 0 ? __expf(x5) : 0.f;                                  \
    float p6 = AJ1[2] > 0 ? __expf(x6) : 0.f;                                  \
    float p7 = AJ1[3] > 0 ? __expf(x7) : 0.f;                                  \
    rs += ((p0 + p1) + (p2 + p3)) + ((p4 + p5) + (p6 + p7));                   \
    unsigned short u0 = __builtin_bit_cast(unsigned short, __float2bfloat16(p0)); \
    unsigned short u1 = __builtin_bit_cast(unsigned short, __float2bfloat16(p1)); \
    unsigned short u2 = __builtin_bit_cast(unsigned short, __float2bfloat16(p2)); \
    unsigned short u3 = __builtin_bit_cast(unsigned short, __float2bfloat16(p3)); \
    unsigned short u4 = __builtin_bit_cast(unsigned short, __float2bfloat16(p4)); \
    unsigned short u5 = __builtin_bit_cast(unsigned short, __float2bfloat16(p5)); \
    unsigned short u6 = __builtin_bit_cast(unsigned short, __float2bfloat16(p6)); \
    unsigned short u7 = __builtin_bit_cast(unsigned short, __float2bfloat16(p7)); \
    int4v pw = {(int)u0 | ((int)u1 << 16), (int)u2 | ((int)u3 << 16),          \
                (int)u4 | ((int)u5 << 16), (int)u6 | ((int)u7 << 16)};         \
    bf16x8 av = __builtin_bit_cast(bf16x8, pw);                                \
    PREF_AF(AJ0,AJ1,F0,F1, (S) + 4);                                           \
    acc0 = __builtin_amdgcn_mfma_f32_16x16x32_bf16(av, B0, acc0, 0, 0, 0);     \
    acc1 = __builtin_amdgcn_mfma_f32_16x16x32_bf16(av, B1, acc1, 0, 0, 0);     \
    acc2 = __builtin_amdgcn_mfma_f32_16x16x32_bf16(av, B2, acc2, 0, 0, 0);     \
    acc3 = __builtin_amdgcn_mfma_f32_16x16x32_bf16(av, B3, acc3, 0, 0, 0);     \
    PREF_BV(B0,B1,B2,B3, (S) + 2);                                             \
  }

  for (int s = s0; s < s1; s += 4) {
    BODY(s,     aA0,aA1,fA0,fA1, bX0,bX1,bX2,bX3);
    BODY(s + 1, aB0,aB1,fB0,fB1, bY0,bY1,bY2,bY3);
    BODY(s + 2, aC0,aC1,fC0,fC1, bX0,bX1,bX2,bX3);
    BODY(s + 3, aD0,aD1,fD0,fD1, bY0,bY1,bY2,bY3);
  }
#undef BODY
#undef PREF_AF
#undef PREF_BV

  // row-sum: combine the 4 lane-groups holding the same row
  rs += __shfl_xor(rs, 16);
  rs += __shfl_xor(rs, 32);
  if (l < 16) prs[(size_t)jc * NN + r0 + l] = rs;

  // partial acc: C layout col = g*16 + (l&15), row = grp*4 + q
  float* pa = pacc + ((size_t)jc * NN + r0 + grp * 4) * FOUT + row;
#pragma unroll
  for (int q = 0; q < 4; ++q) {
    pa[q * FOUT + 0]  = acc0[q];
    pa[q * FOUT + 16] = acc1[q];
    pa[q * FOUT + 32] = acc2[q];
    pa[q * FOUT + 48] = acc3[q];
  }
}

// ---------------------------------------------------------------------------
// kernel 4: combine partials, BN, ELU
// ---------------------------------------------------------------------------
__global__ __launch_bounds__(256) void epilogue_kernel(
    const float* __restrict__ pacc, const float* __restrict__ prs,
    const float* __restrict__ bng, const float* __restrict__ bnb,
    const float* __restrict__ bnm, const float* __restrict__ bnv,
    float* __restrict__ out)
{
  const int idx = blockIdx.x * 256 + threadIdx.x;   // 0 .. NN*FOUT-1
  const int i = idx >> 6;
  const int c = idx & 63;
  float s = 0.f, r = 0.f;
#pragma unroll
  for (int jc = 0; jc < NJC; ++jc) {
    s += pacc[(size_t)jc * NN * FOUT + idx];
    r += prs[(size_t)jc * NN + i];
  }
  float v = s / r;
  v = (v - bnm[c]) * rsqrtf(bnv[c] + 1e-5f) * bng[c] + bnb[c];
  out[idx] = v > 0.f ? v : expm1f(v);
}

// ---------------------------------------------------------------------------
extern "C" void kernel_launch(void* const* d_in, const int* in_sizes, int n_in,
                              void* d_out, int out_size, void* d_ws, size_t ws_size,
                              hipStream_t stream)
{
  (void)in_sizes; (void)n_in; (void)out_size; (void)ws_size;
  const float* inp = (const float*)d_in[0];
  const int*   adj = (const int*)d_in[1];
  const float* Wg  = (const float*)d_in[2];
  const float* ag  = (const float*)d_in[3];
  const float* bng = (const float*)d_in[4];
  const float* bnb = (const float*)d_in[5];
  const float* bnm = (const float*)d_in[6];
  const float* bnv = (const float*)d_in[7];
  float* out = (float*)d_out;

  char* ws = (char*)d_ws;
  unsigned short* hT = (unsigned short*)ws;                    // 1 MiB
  float* f1  = (float*)(ws + (size_t)NN * FOUT * 2);           // 32 KiB
  float* f2  = f1 + NN;                                        // 32 KiB
  float* f2m = f2 + NN;                                        // 4 B
  float* pacc = (float*)(ws + (size_t)2 * 1024 * 1024);        // 6 x 2 MiB
  float* prs  = (float*)(ws + (size_t)2 * 1024 * 1024
                           + (size_t)NJC * NN * FOUT * 4);     // 6 x 32 KiB

  prep_kernel<<<NN / 16, 256, 0, stream>>>(inp, Wg, ag, f1, f2, hT);
  f2max_kernel<<<1, 256, 0, stream>>>(f2, f2m);
  gat_pv<<<(512 * NJC) / 4, 256, 0, stream>>>(adj, f1, f2, f2m, hT, pacc, prs);
  epilogue_kernel<<<NN * FOUT / 256, 256, 0, stream>>>(pacc, prs, bng, bnb,
                                                       bnm, bnv, out);
}

// Round 4
// 142.496 us; speedup vs baseline: 1.3216x; 1.3216x over previous
//
#include <hip/hip_runtime.h>
#include <hip/hip_bf16.h>

#define LRALPHA 0.2f
#define NN 8192
#define FIN 128
#define FOUT 64
#define TI 16
#define TJ 256
#define NTL (NN / TJ)   // 32 tiles

typedef __attribute__((ext_vector_type(4))) float f32x4;
typedef __attribute__((ext_vector_type(8))) short bf16x8;
typedef __attribute__((ext_vector_type(4))) int int4v;

__device__ __forceinline__ void barrier_lgkm() {
  asm volatile("s_waitcnt lgkmcnt(0)\n\ts_barrier" ::: "memory");
}

// ---------------------------------------------------------------------------
// kernel 0: adj (268 MB int32) -> 1-bit mask (8 MB), PERFECTLY LINEAR read.
// chunk c = 256 consecutive ints; lane l reads cols e*64+l (dword, dense);
// ballot bit l = col e*64+l  ->  mask64[c*4+e].
// ---------------------------------------------------------------------------
__global__ __launch_bounds__(256) void compress_kernel(
    const int* __restrict__ adj, unsigned long long* __restrict__ mask)
{
  const int l = threadIdx.x & 63;
  const int wid = (blockIdx.x * 256 + threadIdx.x) >> 6;
  const int nw = (gridDim.x * 256) >> 6;
  const int nchunks = NN * (NN / 256);
  for (int c = wid; c < nchunks; c += nw) {
    const int* base = adj + (size_t)c * 256;
    int a0 = __builtin_nontemporal_load(base + l);
    int a1 = __builtin_nontemporal_load(base + 64 + l);
    int a2 = __builtin_nontemporal_load(base + 128 + l);
    int a3 = __builtin_nontemporal_load(base + 192 + l);
    unsigned long long b0 = __ballot(a0 > 0);
    unsigned long long b1 = __ballot(a1 > 0);
    unsigned long long b2 = __ballot(a2 > 0);
    unsigned long long b3 = __ballot(a3 > 0);
    if (l < 4) {
      unsigned long long v = l == 0 ? b0 : (l == 1 ? b1 : (l == 2 ? b2 : b3));
      mask[(size_t)c * 4 + l] = v;
    }
  }
}

// ---------------------------------------------------------------------------
// kernel 1: h = inp @ W (fp32), f1 = h@a1, f2 = h@a2, hT[c][row] in bf16
// ---------------------------------------------------------------------------
__global__ __launch_bounds__(256) void prep_kernel(
    const float* __restrict__ inp, const float* __restrict__ Wg,
    const float* __restrict__ ag, float* __restrict__ f1,
    float* __restrict__ f2, unsigned short* __restrict__ hT)
{
  __shared__ alignas(16) float WlT[FOUT][FIN + 4];
  const int t = threadIdx.x;
  for (int i = t; i < FIN * FOUT; i += 256)
    WlT[i & 63][i >> 6] = Wg[i];
  __syncthreads();

  const int lane = t & 63;
  const int row0 = blockIdx.x * 16 + (t >> 6) * 4;

  float h0 = 0.f, h1 = 0.f, h2 = 0.f, h3 = 0.f;
  for (int kk = 0; kk < FIN; kk += 4) {
    f32x4 wv = *(const f32x4*)&WlT[lane][kk];
    f32x4 r0 = *(const f32x4*)&inp[(row0 + 0) * FIN + kk];
    f32x4 r1 = *(const f32x4*)&inp[(row0 + 1) * FIN + kk];
    f32x4 r2 = *(const f32x4*)&inp[(row0 + 2) * FIN + kk];
    f32x4 r3 = *(const f32x4*)&inp[(row0 + 3) * FIN + kk];
    h0 += r0[0]*wv[0] + r0[1]*wv[1] + r0[2]*wv[2] + r0[3]*wv[3];
    h1 += r1[0]*wv[0] + r1[1]*wv[1] + r1[2]*wv[2] + r1[3]*wv[3];
    h2 += r2[0]*wv[0] + r2[1]*wv[1] + r2[2]*wv[2] + r2[3]*wv[3];
    h3 += r3[0]*wv[0] + r3[1]*wv[1] + r3[2]*wv[2] + r3[3]*wv[3];
  }

  const float a1v = ag[lane], a2v = ag[64 + lane];
  float hv[4] = {h0, h1, h2, h3};
#pragma unroll
  for (int rr = 0; rr < 4; ++rr) {
    float c1 = hv[rr] * a1v;
    float c2 = hv[rr] * a2v;
#pragma unroll
    for (int off = 32; off > 0; off >>= 1) {
      c1 += __shfl_xor(c1, off);
      c2 += __shfl_xor(c2, off);
    }
    if (lane == 0) { f1[row0 + rr] = c1; f2[row0 + rr] = c2; }
    __hip_bfloat16 hb = __float2bfloat16(hv[rr]);
    hT[lane * NN + row0 + rr] = __builtin_bit_cast(unsigned short, hb);
  }
}

// ---------------------------------------------------------------------------
// kernel 2: global max of f2
// ---------------------------------------------------------------------------
__global__ __launch_bounds__(256) void f2max_kernel(
    const float* __restrict__ f2, float* __restrict__ f2m)
{
  const int t = threadIdx.x;
  float m = -1e30f;
  for (int i = t; i < NN / 4; i += 256) {
    f32x4 v = ((const f32x4*)f2)[i];
    m = fmaxf(fmaxf(m, fmaxf(v[0], v[1])), fmaxf(v[2], v[3]));
  }
#pragma unroll
  for (int off = 32; off > 0; off >>= 1)
    m = fmaxf(m, __shfl_xor(m, off));
  __shared__ float ms[4];
  if ((t & 63) == 0) ms[t >> 6] = m;
  __syncthreads();
  if (t == 0)
    f2m[0] = fmaxf(fmaxf(ms[0], ms[1]), fmaxf(ms[2], ms[3]));
}

// ---------------------------------------------------------------------------
// kernel 3: fused masked-softmax attention + BN + ELU, fed from the bitmask.
// block = 256 thr (4 waves), TI=16 rows, TJ=256 tiles, quad-buffered P tile,
// ONE lgkm barrier per tile. B-fragments read directly from L2-resident hT.
// Wave w produces rows 4w..4w+3; consumes cols w*16..w*16+15.
// ---------------------------------------------------------------------------
__global__ __launch_bounds__(256, 4) void gat_main(
    const unsigned long long* __restrict__ mask,
    const float* __restrict__ f1g, const float* __restrict__ f2g,
    const float* __restrict__ f2m, const unsigned short* __restrict__ hTg,
    const float* __restrict__ bng, const float* __restrict__ bnb,
    const float* __restrict__ bnm, const float* __restrict__ bnv,
    float* __restrict__ out)
{
  __shared__ alignas(16) unsigned short Pl[4][TI][TJ + 8];  // quad-buffered
  __shared__ float rs_lds[TI];

  const int t = threadIdx.x;
  const int l = t & 63;
  const int w = t >> 6;
  const int i0 = blockIdx.x * TI;
  const int g = l >> 4;           // 0..3

  const float fmv = f2m[0];
  float f1q[4], mrow[4];
#pragma unroll
  for (int q = 0; q < 4; ++q) {
    f1q[q] = f1g[i0 + 4 * w + q];
    float m = f1q[q] + fmv;
    mrow[q] = fmaxf(m, LRALPHA * m);
  }

  // mask address for row 4w+q, tile p: mask[((i0+4w+q)*32 + p)*4 + g]
  const unsigned long long* mrow0 = mask + ((size_t)(i0 + 4 * w + 0) * NTL) * 4 + g;
  const unsigned long long* mrow1 = mask + ((size_t)(i0 + 4 * w + 1) * NTL) * 4 + g;
  const unsigned long long* mrow2 = mask + ((size_t)(i0 + 4 * w + 2) * NTL) * 4 + g;
  const unsigned long long* mrow3 = mask + ((size_t)(i0 + 4 * w + 3) * NTL) * 4 + g;
  const int mshift = (l & 15) * 4;

  const float* f2p = f2g + 4 * l;
  const unsigned short* hp = hTg + (size_t)(w * 16 + (l & 15)) * NN + g * 8;
  const unsigned short* pAp = &Pl[0][l & 15][g * 8];

  f32x4 acc = {0.f, 0.f, 0.f, 0.f};
  float rs0 = 0.f, rs1 = 0.f, rs2 = 0.f, rs3 = 0.f;

  // produce tile p into Pl[p&3] from registers (mm0..3, ff)
#define PRODUCE(P, MM0, MM1, MM2, MM3, FF)                                     \
  {                                                                            \
    unsigned n0 = (unsigned)(MM0 >> mshift) & 0xF;                             \
    unsigned n1 = (unsigned)(MM1 >> mshift) & 0xF;                             \
    unsigned n2 = (unsigned)(MM2 >> mshift) & 0xF;                             \
    unsigned n3 = (unsigned)(MM3 >> mshift) & 0xF;                             \
    _Pragma("unroll")                                                          \
    for (int q = 0; q < 4; ++q) {                                              \
      unsigned nib = q == 0 ? n0 : (q == 1 ? n1 : (q == 2 ? n2 : n3));         \
      float y0 = f1q[q] + FF[0]; y0 = fmaxf(y0, LRALPHA * y0) - mrow[q];       \
      float y1 = f1q[q] + FF[1]; y1 = fmaxf(y1, LRALPHA * y1) - mrow[q];       \
      float y2 = f1q[q] + FF[2]; y2 = fmaxf(y2, LRALPHA * y2) - mrow[q];       \
      float y3 = f1q[q] + FF[3]; y3 = fmaxf(y3, LRALPHA * y3) - mrow[q];       \
      float p0 = (nib & 1u) ? __expf(y0) : 0.f;                                \
      float p1 = (nib & 2u) ? __expf(y1) : 0.f;                                \
      float p2 = (nib & 4u) ? __expf(y2) : 0.f;                                \
      float p3 = (nib & 8u) ? __expf(y3) : 0.f;                                \
      if (q == 0) rs0 += (p0 + p1) + (p2 + p3);                                \
      if (q == 1) rs1 += (p0 + p1) + (p2 + p3);                                \
      if (q == 2) rs2 += (p0 + p1) + (p2 + p3);                                \
      if (q == 3) rs3 += (p0 + p1) + (p2 + p3);                                \
      unsigned short u0 = __builtin_bit_cast(unsigned short, __float2bfloat16(p0)); \
      unsigned short u1 = __builtin_bit_cast(unsigned short, __float2bfloat16(p1)); \
      unsigned short u2 = __builtin_bit_cast(unsigned short, __float2bfloat16(p2)); \
      unsigned short u3 = __builtin_bit_cast(unsigned short, __float2bfloat16(p3)); \
      unsigned long long pk = (unsigned long long)u0 |                         \
                              ((unsigned long long)u1 << 16) |                 \
                              ((unsigned long long)u2 << 32) |                 \
                              ((unsigned long long)u3 << 48);                  \
      *(unsigned long long*)&Pl[(P) & 3][4 * w + q][4 * l] = pk;               \
    }                                                                          \
  }

#define LOADR(MM0, MM1, MM2, MM3, FF, P)                                       \
  { int _p = (P) < NTL ? (P) : (NTL - 1);                                      \
    MM0 = mrow0[_p * 4]; MM1 = mrow1[_p * 4];                                  \
    MM2 = mrow2[_p * 4]; MM3 = mrow3[_p * 4];                                  \
    FF = *(const f32x4*)(f2p + _p * TJ); }

  unsigned long long m0, m1, m2, m3;
  f32x4 ff;

  // prologue: produce tiles 0 and 1
  LOADR(m0, m1, m2, m3, ff, 0);
  PRODUCE(0, m0, m1, m2, m3, ff);
  LOADR(m0, m1, m2, m3, ff, 1);
  PRODUCE(1, m0, m1, m2, m3, ff);
  LOADR(m0, m1, m2, m3, ff, 2);

  for (int tt = 0; tt < NTL; ++tt) {
    if (tt < NTL - 2) {
      PRODUCE(tt + 2, m0, m1, m2, m3, ff);
      LOADR(m0, m1, m2, m3, ff, tt + 3);
    }
    barrier_lgkm();
    // consume tile tt: 8 k-windows of 32
    const unsigned short* pa = pAp + (size_t)(tt & 3) * TI * (TJ + 8);
    const unsigned short* pb = hp + (size_t)tt * TJ;
#pragma unroll
    for (int kw = 0; kw < 8; ++kw) {
      bf16x8 av = *(const bf16x8*)(pa + kw * 32);
      bf16x8 bv = *(const bf16x8*)(pb + kw * 32);
      acc = __builtin_amdgcn_mfma_f32_16x16x32_bf16(av, bv, acc, 0, 0, 0);
    }
  }
#undef PRODUCE
#undef LOADR

  // row sums: reduce each rs_q across the full wave
  float rsq[4] = {rs0, rs1, rs2, rs3};
#pragma unroll
  for (int q = 0; q < 4; ++q) {
    float r = rsq[q];
#pragma unroll
    for (int off = 32; off > 0; off >>= 1)
      r += __shfl_xor(r, off);
    if (l == 0) rs_lds[4 * w + q] = r;
  }
  __syncthreads();

  // epilogue: divide by row sum, batch norm, ELU
  const int gcol = w * 16 + (l & 15);
  const float inv_sd = rsqrtf(bnv[gcol] + 1e-5f);
  const float ga = bng[gcol], be = bnb[gcol], mu = bnm[gcol];
  const int rbase = g * 4;
#pragma unroll
  for (int q = 0; q < 4; ++q) {
    float v = acc[q] / rs_lds[rbase + q];
    v = (v - mu) * inv_sd * ga + be;
    v = v > 0.f ? v : expm1f(v);
    out[(size_t)(i0 + rbase + q) * FOUT + gcol] = v;
  }
}

// ---------------------------------------------------------------------------
extern "C" void kernel_launch(void* const* d_in, const int* in_sizes, int n_in,
                              void* d_out, int out_size, void* d_ws, size_t ws_size,
                              hipStream_t stream)
{
  (void)in_sizes; (void)n_in; (void)out_size; (void)ws_size;
  const float* inp = (const float*)d_in[0];
  const int*   adj = (const int*)d_in[1];
  const float* Wg  = (const float*)d_in[2];
  const float* ag  = (const float*)d_in[3];
  const float* bng = (const float*)d_in[4];
  const float* bnb = (const float*)d_in[5];
  const float* bnm = (const float*)d_in[6];
  const float* bnv = (const float*)d_in[7];
  float* out = (float*)d_out;

  char* ws = (char*)d_ws;
  unsigned short* hT = (unsigned short*)ws;                    // 1 MiB
  float* f1  = (float*)(ws + (size_t)NN * FOUT * 2);           // 32 KiB
  float* f2  = f1 + NN;                                        // 32 KiB
  float* f2m = f2 + NN;                                        // 4 B
  unsigned long long* mask =
      (unsigned long long*)(ws + (size_t)2 * 1024 * 1024);     // 8 MiB

  compress_kernel<<<2048, 256, 0, stream>>>(adj, mask);
  prep_kernel<<<NN / 16, 256, 0, stream>>>(inp, Wg, ag, f1, f2, hT);
  f2max_kernel<<<1, 256, 0, stream>>>(f2, f2m);
  gat_main<<<NN / TI, 256, 0, stream>>>(mask, f1, f2, f2m, hT,
                                        bng, bnb, bnm, bnv, out);
}